// Round 1
// baseline (1851.123 us; speedup 1.0000x reference)
//
#include <hip/hip_runtime.h>
#include <math.h>

#define H    24
#define Dh   128
#define LIMG 2048
#define LIP  512
#define DM   3072
#define DIP  1280
#define LK   (LIMG + LIP)   // 2560
#define EPSF 1e-6f
#define SM_SCALE 0.08838834764831845f  // 1/sqrt(128)

// ---------------- Kernel 1: e = silu(t_emb) @ w_ada^T + b_ada ----------------
__global__ __launch_bounds__(256) void ada_kernel(
    const float* __restrict__ t_emb, const float* __restrict__ w_ada,
    const float* __restrict__ b_ada, float* __restrict__ e) {
  int j = blockIdx.x;
  int tid = threadIdx.x;
  const float* wrow = w_ada + (long)j * DIP;
  float acc = 0.f;
  for (int k = tid; k < DIP; k += 256) {
    float t = t_emb[k];
    float s = t / (1.f + expf(-t));   // silu
    acc += s * wrow[k];
  }
#pragma unroll
  for (int m = 1; m < 64; m <<= 1) acc += __shfl_xor(acc, m, 64);
  __shared__ float red[4];
  if ((tid & 63) == 0) red[tid >> 6] = acc;
  __syncthreads();
  if (tid == 0) e[j] = red[0] + red[1] + red[2] + red[3] + b_ada[j];
}

// ---------------- Kernel 2: AdaLayerNorm -> ip_norm ----------------
__global__ __launch_bounds__(256) void adaln_kernel(
    const float* __restrict__ x, const float* __restrict__ e,
    float* __restrict__ ipn) {
  int r = blockIdx.x;
  int tid = threadIdx.x;
  const float* xr = x + (long)r * DIP;
  float v[5];
  float s = 0.f, ss = 0.f;
#pragma unroll
  for (int i = 0; i < 5; i++) {
    v[i] = xr[tid + i * 256];
    s += v[i];
    ss += v[i] * v[i];
  }
#pragma unroll
  for (int m = 1; m < 64; m <<= 1) {
    s += __shfl_xor(s, m, 64);
    ss += __shfl_xor(ss, m, 64);
  }
  __shared__ float rs_[4], rss_[4];
  if ((tid & 63) == 0) { rs_[tid >> 6] = s; rss_[tid >> 6] = ss; }
  __syncthreads();
  s = rs_[0] + rs_[1] + rs_[2] + rs_[3];
  ss = rss_[0] + rss_[1] + rss_[2] + rss_[3];
  float mu = s * (1.f / DIP);
  float var = ss * (1.f / DIP) - mu * mu;
  float rstd = rsqrtf(var + EPSF);
  float* outr = ipn + (long)r * DIP;
#pragma unroll
  for (int i = 0; i < 5; i++) {
    int c = tid + i * 256;
    outr[c] = (v[i] - mu) * rstd * (1.f + e[DIP + c]) + e[c];
  }
}

// ---------------- Kernel 3: ipk = ipn @ Wk^T, ipv = ipn @ Wv^T ----------------
// C[m][n] = sum_k A[m][k]*W[n][k]; M=512, N=3072, K=1280. BM=BN=64, BK=16, 4x4/thread.
__global__ __launch_bounds__(256) void proj_kernel(
    const float* __restrict__ A, const float* __restrict__ Wk,
    const float* __restrict__ Wv, float* __restrict__ Ck, float* __restrict__ Cv) {
  const float* W = blockIdx.z ? Wv : Wk;
  float* C = blockIdx.z ? Cv : Ck;
  int n0 = blockIdx.x * 64, m0 = blockIdx.y * 64;
  __align__(16) __shared__ float As[16][64];
  __align__(16) __shared__ float Ws[16][64];
  int tid = threadIdx.x;
  int tx = tid & 15, ty = tid >> 4;
  int lm = tid >> 2, lk = tid & 3;
  float acc[4][4] = {};
#pragma unroll 1
  for (int k0 = 0; k0 < DIP; k0 += 16) {
    float4 a4 = *(const float4*)(A + (long)(m0 + lm) * DIP + k0 + lk * 4);
    float4 w4 = *(const float4*)(W + (long)(n0 + lm) * DIP + k0 + lk * 4);
    __syncthreads();
    As[lk * 4 + 0][lm] = a4.x; As[lk * 4 + 1][lm] = a4.y;
    As[lk * 4 + 2][lm] = a4.z; As[lk * 4 + 3][lm] = a4.w;
    Ws[lk * 4 + 0][lm] = w4.x; Ws[lk * 4 + 1][lm] = w4.y;
    Ws[lk * 4 + 2][lm] = w4.z; Ws[lk * 4 + 3][lm] = w4.w;
    __syncthreads();
#pragma unroll
    for (int kk = 0; kk < 16; kk++) {
      float4 av = *(const float4*)&As[kk][ty * 4];
      float4 wv = *(const float4*)&Ws[kk][tx * 4];
      float a_[4] = {av.x, av.y, av.z, av.w};
      float b_[4] = {wv.x, wv.y, wv.z, wv.w};
#pragma unroll
      for (int i = 0; i < 4; i++)
#pragma unroll
        for (int j2 = 0; j2 < 4; j2++) acc[i][j2] += a_[i] * b_[j2];
    }
  }
#pragma unroll
  for (int i = 0; i < 4; i++) {
    float4 o = make_float4(acc[i][0], acc[i][1], acc[i][2], acc[i][3]);
    *(float4*)(C + (long)(m0 + ty * 4 + i) * DM + n0 + tx * 4) = o;
  }
}

// ---------------- Kernel 4: flash attention, fp32, fused RMS norms ----------------
// TQ=64 q-rows per block, TK=32 k-rows per tile, 256 threads.
// LDS in float4 units, XOR-swizzled: element (row r, f4-col i) at slot [r*32 + (i ^ (r&31))]
__global__ __launch_bounds__(256) void flash_kernel(
    const float* __restrict__ q_in, const float* __restrict__ k_in,
    const float* __restrict__ v_in, const float* __restrict__ ipk,
    const float* __restrict__ ipv, const float* __restrict__ g_q,
    const float* __restrict__ g_k, const float* __restrict__ g_ipk,
    float* __restrict__ out) {
  __shared__ float4 Qs4[64 * 32];   // 32 KB
  __shared__ float4 Ks4[32 * 32];   // 16 KB
  __shared__ float4 Vs4[32 * 32];   // 16 KB  -> exactly 64 KB total
  int tid = threadIdx.x;
  int h = blockIdx.y;
  int q0 = blockIdx.x * 64;

  // ---- Q tile load + RMS norm (4 threads per row, 8 float4 each) ----
  {
    int r = tid >> 2;
    int c4 = tid & 3;
    const float* src = q_in + (long)(q0 + r) * DM + h * Dh;
    float4 vals[8];
    float ssq = 0.f;
#pragma unroll
    for (int qq = 0; qq < 8; qq++) {
      int i = c4 + 4 * qq;
      vals[qq] = *(const float4*)(src + i * 4);
      ssq += vals[qq].x * vals[qq].x + vals[qq].y * vals[qq].y +
             vals[qq].z * vals[qq].z + vals[qq].w * vals[qq].w;
    }
    ssq += __shfl_xor(ssq, 1, 4);
    ssq += __shfl_xor(ssq, 2, 4);
    float rstd = rsqrtf(ssq * (1.f / Dh) + EPSF);
#pragma unroll
    for (int qq = 0; qq < 8; qq++) {
      int i = c4 + 4 * qq;
      float4 g4 = *(const float4*)(g_q + i * 4);
      float4 v4 = vals[qq];
      v4.x *= rstd * g4.x; v4.y *= rstd * g4.y;
      v4.z *= rstd * g4.z; v4.w *= rstd * g4.w;
      Qs4[r * 32 + (i ^ (r & 31))] = v4;
    }
  }

  int qy = tid >> 3;   // 0..31 -> owns q-rows qy and qy+32
  int kg = tid & 7;    // col group: k-cols {kg + 8c}, v f4-cols {kg + 8i}
  int rK = tid >> 3;   // K/V staging row
  int cK = tid & 7;

  float m0r = -INFINITY, m1r = -INFINITY, l0 = 0.f, l1 = 0.f;
  float4 O0[4] = {}, O1[4] = {};

#pragma unroll 1
  for (int j0 = 0; j0 < LK; j0 += 32) {
    // ---- load K (with RMS) and V into registers ----
    int jj = j0 + rK;
    const float* ksrc; const float* vsrc; const float* gk;
    if (jj < LIMG) {
      ksrc = k_in + (long)jj * DM + h * Dh;
      vsrc = v_in + (long)jj * DM + h * Dh;
      gk = g_k;
    } else {
      ksrc = ipk + (long)(jj - LIMG) * DM + h * Dh;
      vsrc = ipv + (long)(jj - LIMG) * DM + h * Dh;
      gk = g_ipk;
    }
    float4 kv[4], vv[4];
    float ssq = 0.f;
#pragma unroll
    for (int qq = 0; qq < 4; qq++) {
      int i = cK + 8 * qq;
      kv[qq] = *(const float4*)(ksrc + i * 4);
      vv[qq] = *(const float4*)(vsrc + i * 4);
      ssq += kv[qq].x * kv[qq].x + kv[qq].y * kv[qq].y +
             kv[qq].z * kv[qq].z + kv[qq].w * kv[qq].w;
    }
    ssq += __shfl_xor(ssq, 1, 8);
    ssq += __shfl_xor(ssq, 2, 8);
    ssq += __shfl_xor(ssq, 4, 8);
    float rstd = rsqrtf(ssq * (1.f / Dh) + EPSF);

    __syncthreads();   // previous tile's compute done reading Ks/Vs
#pragma unroll
    for (int qq = 0; qq < 4; qq++) {
      int i = cK + 8 * qq;
      float4 g4 = *(const float4*)(gk + i * 4);
      float4 t4 = kv[qq];
      t4.x *= rstd * g4.x; t4.y *= rstd * g4.y;
      t4.z *= rstd * g4.z; t4.w *= rstd * g4.w;
      Ks4[rK * 32 + (i ^ (rK & 31))] = t4;
      Vs4[rK * 32 + (i ^ (rK & 31))] = vv[qq];
    }
    __syncthreads();

    // ---- S = Q K^T : 2 rows x 4 cols per thread ----
    float s0[4] = {}, s1[4] = {};
#pragma unroll 8
    for (int d4 = 0; d4 < 32; d4++) {
      float4 qa = Qs4[qy * 32 + (d4 ^ (qy & 31))];
      float4 qb = Qs4[(qy + 32) * 32 + (d4 ^ (qy & 31))];
#pragma unroll
      for (int c = 0; c < 4; c++) {
        int j = kg + 8 * c;
        float4 k4 = Ks4[j * 32 + (d4 ^ (j & 31))];
        s0[c] += qa.x * k4.x + qa.y * k4.y + qa.z * k4.z + qa.w * k4.w;
        s1[c] += qb.x * k4.x + qb.y * k4.y + qb.z * k4.z + qb.w * k4.w;
      }
    }
#pragma unroll
    for (int c = 0; c < 4; c++) { s0[c] *= SM_SCALE; s1[c] *= SM_SCALE; }

    // ---- online softmax (row split over 8 lanes) ----
    float mt0 = fmaxf(fmaxf(s0[0], s0[1]), fmaxf(s0[2], s0[3]));
    float mt1 = fmaxf(fmaxf(s1[0], s1[1]), fmaxf(s1[2], s1[3]));
    mt0 = fmaxf(mt0, __shfl_xor(mt0, 1, 8));
    mt0 = fmaxf(mt0, __shfl_xor(mt0, 2, 8));
    mt0 = fmaxf(mt0, __shfl_xor(mt0, 4, 8));
    mt1 = fmaxf(mt1, __shfl_xor(mt1, 1, 8));
    mt1 = fmaxf(mt1, __shfl_xor(mt1, 2, 8));
    mt1 = fmaxf(mt1, __shfl_xor(mt1, 4, 8));
    float mn0 = fmaxf(m0r, mt0), mn1 = fmaxf(m1r, mt1);
    float p0[4], p1[4];
    float lt0 = 0.f, lt1 = 0.f;
#pragma unroll
    for (int c = 0; c < 4; c++) {
      p0[c] = __expf(s0[c] - mn0); lt0 += p0[c];
      p1[c] = __expf(s1[c] - mn1); lt1 += p1[c];
    }
    lt0 += __shfl_xor(lt0, 1, 8); lt0 += __shfl_xor(lt0, 2, 8); lt0 += __shfl_xor(lt0, 4, 8);
    lt1 += __shfl_xor(lt1, 1, 8); lt1 += __shfl_xor(lt1, 2, 8); lt1 += __shfl_xor(lt1, 4, 8);
    float a0 = __expf(m0r - mn0), a1 = __expf(m1r - mn1);
    m0r = mn0; m1r = mn1;
    l0 = l0 * a0 + lt0;
    l1 = l1 * a1 + lt1;
#pragma unroll
    for (int i = 0; i < 4; i++) {
      O0[i].x *= a0; O0[i].y *= a0; O0[i].z *= a0; O0[i].w *= a0;
      O1[i].x *= a1; O1[i].y *= a1; O1[i].z *= a1; O1[i].w *= a1;
    }
    // ---- O += P V ----
#pragma unroll
    for (int j = 0; j < 32; j++) {
      float pj0 = __shfl(p0[j >> 3], j & 7, 8);
      float pj1 = __shfl(p1[j >> 3], j & 7, 8);
#pragma unroll
      for (int i2 = 0; i2 < 4; i2++) {
        int i = kg + 8 * i2;
        float4 v4 = Vs4[j * 32 + (i ^ (j & 31))];
        O0[i2].x += pj0 * v4.x; O0[i2].y += pj0 * v4.y;
        O0[i2].z += pj0 * v4.z; O0[i2].w += pj0 * v4.w;
        O1[i2].x += pj1 * v4.x; O1[i2].y += pj1 * v4.y;
        O1[i2].z += pj1 * v4.z; O1[i2].w += pj1 * v4.w;
      }
    }
  }

  // ---- epilogue: O /= l, write out[l, h*128 + col] ----
  float il0 = 1.f / l0, il1 = 1.f / l1;
  float* o0 = out + (long)(q0 + qy) * DM + h * Dh;
  float* o1 = out + (long)(q0 + qy + 32) * DM + h * Dh;
#pragma unroll
  for (int i2 = 0; i2 < 4; i2++) {
    int i = kg + 8 * i2;
    float4 t0 = O0[i2], t1 = O1[i2];
    t0.x *= il0; t0.y *= il0; t0.z *= il0; t0.w *= il0;
    t1.x *= il1; t1.y *= il1; t1.z *= il1; t1.w *= il1;
    *(float4*)(o0 + i * 4) = t0;
    *(float4*)(o1 + i * 4) = t1;
  }
}

// ---------------- launch ----------------
extern "C" void kernel_launch(void* const* d_in, const int* in_sizes, int n_in,
                              void* d_out, int out_size, void* d_ws, size_t ws_size,
                              hipStream_t stream) {
  const float* ip_hidden = (const float*)d_in[0];
  const float* img_q     = (const float*)d_in[1];
  const float* img_k     = (const float*)d_in[2];
  const float* img_v     = (const float*)d_in[3];
  const float* t_emb     = (const float*)d_in[4];
  const float* w_ada     = (const float*)d_in[5];
  const float* b_ada     = (const float*)d_in[6];
  const float* w_k_ip    = (const float*)d_in[7];
  const float* w_v_ip    = (const float*)d_in[8];
  const float* g_q       = (const float*)d_in[9];
  const float* g_k       = (const float*)d_in[10];
  const float* g_ipk     = (const float*)d_in[11];
  float* ws  = (float*)d_ws;
  float* e   = ws;                    // 2560 used, 4096 reserved
  float* ipn = ws + 4096;             // 512*1280
  float* ipk = ipn + (long)LIP * DIP; // 512*3072
  float* ipv = ipk + (long)LIP * DM;  // 512*3072
  float* out = (float*)d_out;

  ada_kernel<<<2560, 256, 0, stream>>>(t_emb, w_ada, b_ada, e);
  adaln_kernel<<<LIP, 256, 0, stream>>>(ip_hidden, e, ipn);
  proj_kernel<<<dim3(48, 8, 2), 256, 0, stream>>>(ipn, w_k_ip, w_v_ip, ipk, ipv);
  flash_kernel<<<dim3(32, 24), 256, 0, stream>>>(img_q, img_k, img_v, ipk, ipv,
                                                 g_q, g_k, g_ipk, out);
}

// Round 2
// 482.904 us; speedup vs baseline: 3.8333x; 3.8333x over previous
//
#include <hip/hip_runtime.h>
#include <math.h>

#define H    24
#define Dh   128
#define LIMG 2048
#define LIP  512
#define DM   3072
#define DIP  1280
#define LK   2560
#define EPSF 1e-6f
#define SM_SCALE 0.08838834764831845f  // 1/sqrt(128)

typedef __attribute__((ext_vector_type(8))) short bf16x8;
typedef __attribute__((ext_vector_type(4))) float f32x4;

typedef const unsigned int __attribute__((address_space(1))) gu32;
typedef unsigned int __attribute__((address_space(3))) lu32;

static __device__ __forceinline__ unsigned short f2bf(float x) {
  union { float f; unsigned u; } v; v.f = x;
  unsigned r = v.u + 0x7fffu + ((v.u >> 16) & 1u);  // RNE
  return (unsigned short)(r >> 16);
}

// ---------------- Kernel 1: e = silu(t_emb) @ w_ada^T + b_ada ----------------
__global__ __launch_bounds__(256) void ada_kernel(
    const float* __restrict__ t_emb, const float* __restrict__ w_ada,
    const float* __restrict__ b_ada, float* __restrict__ e) {
  int j = blockIdx.x;
  int tid = threadIdx.x;
  const float* wrow = w_ada + (long)j * DIP;
  float acc = 0.f;
  for (int k = tid; k < DIP; k += 256) {
    float t = t_emb[k];
    acc += (t / (1.f + expf(-t))) * wrow[k];
  }
#pragma unroll
  for (int m = 1; m < 64; m <<= 1) acc += __shfl_xor(acc, m, 64);
  __shared__ float red[4];
  if ((tid & 63) == 0) red[tid >> 6] = acc;
  __syncthreads();
  if (tid == 0) e[j] = red[0] + red[1] + red[2] + red[3] + b_ada[j];
}

// ---------------- Kernel 2: AdaLayerNorm -> ip_norm (fp32) ----------------
__global__ __launch_bounds__(256) void adaln_kernel(
    const float* __restrict__ x, const float* __restrict__ e,
    float* __restrict__ ipn) {
  int r = blockIdx.x;
  int tid = threadIdx.x;
  const float* xr = x + (long)r * DIP;
  float v[5];
  float s = 0.f, ss = 0.f;
#pragma unroll
  for (int i = 0; i < 5; i++) {
    v[i] = xr[tid + i * 256];
    s += v[i];
    ss += v[i] * v[i];
  }
#pragma unroll
  for (int m = 1; m < 64; m <<= 1) {
    s += __shfl_xor(s, m, 64);
    ss += __shfl_xor(ss, m, 64);
  }
  __shared__ float rs_[4], rss_[4];
  if ((tid & 63) == 0) { rs_[tid >> 6] = s; rss_[tid >> 6] = ss; }
  __syncthreads();
  s = rs_[0] + rs_[1] + rs_[2] + rs_[3];
  ss = rss_[0] + rss_[1] + rss_[2] + rss_[3];
  float mu = s * (1.f / DIP);
  float var = ss * (1.f / DIP) - mu * mu;
  float rstd = rsqrtf(var + EPSF);
  float* outr = ipn + (long)r * DIP;
#pragma unroll
  for (int i = 0; i < 5; i++) {
    int c = tid + i * 256;
    outr[c] = (v[i] - mu) * rstd * (1.f + e[DIP + c]) + e[c];
  }
}

// ---------------- Kernel 3: img K (RMS) -> Kb bf16, img V -> Vt bf16 (transposed) --
// Kb[H][LK][128] row-major; Vt[H][128][LK]. Block = (32 rows, 1 head).
__global__ __launch_bounds__(256) void prep_kernel(
    const float* __restrict__ k_in, const float* __restrict__ v_in,
    const float* __restrict__ g_k,
    unsigned short* __restrict__ Kb, unsigned short* __restrict__ Vt) {
  __shared__ unsigned short Vls[128][33];
  int h = blockIdx.y, l0 = blockIdx.x * 32;
  int tid = threadIdx.x;
  int r = tid >> 3, c = tid & 7;   // 8 threads/row, 16 elems each
  const float* ksrc = k_in + (long)(l0 + r) * DM + h * Dh + c * 16;
  const float* vsrc = v_in + (long)(l0 + r) * DM + h * Dh + c * 16;
  float kv[16], vv[16];
  float ssq = 0.f;
#pragma unroll
  for (int i = 0; i < 4; i++) {
    float4 a = *(const float4*)(ksrc + i * 4);
    float4 b = *(const float4*)(vsrc + i * 4);
    kv[i*4+0]=a.x; kv[i*4+1]=a.y; kv[i*4+2]=a.z; kv[i*4+3]=a.w;
    vv[i*4+0]=b.x; vv[i*4+1]=b.y; vv[i*4+2]=b.z; vv[i*4+3]=b.w;
    ssq += a.x*a.x + a.y*a.y + a.z*a.z + a.w*a.w;
  }
  ssq += __shfl_xor(ssq, 1, 8);
  ssq += __shfl_xor(ssq, 2, 8);
  ssq += __shfl_xor(ssq, 4, 8);
  float rstd = rsqrtf(ssq * (1.f / Dh) + EPSF);
  unsigned short kb[16];
#pragma unroll
  for (int i = 0; i < 16; i++) kb[i] = f2bf(kv[i] * rstd * g_k[c * 16 + i]);
  unsigned short* kdst = Kb + ((long)h * LK + l0 + r) * Dh + c * 16;
  *(uint4*)(kdst) = *(uint4*)(kb);
  *(uint4*)(kdst + 8) = *(uint4*)(kb + 8);
  // transpose V through LDS
#pragma unroll
  for (int i = 0; i < 16; i++) Vls[c * 16 + i][r] = f2bf(vv[i]);
  __syncthreads();
  int d = tid >> 1, half = (tid & 1) * 16;
  unsigned short ov[16];
#pragma unroll
  for (int j = 0; j < 16; j++) ov[j] = Vls[d][half + j];
  unsigned short* vdst = Vt + ((long)h * Dh + d) * LK + l0 + half;
  *(uint4*)(vdst) = *(uint4*)(ov);
  *(uint4*)(vdst + 8) = *(uint4*)(ov + 8);
}

// ---------------- Kernel 4: ip projections, fused epilogues ----------------
// C[m][n] = sum_k ipn[m][k] * W[n][k]; M=512, N=128 (one head/block), K=1280.
// z=0: RMS(+g_ipk) -> Kb rows 2048+; z=1: transposed -> Vt cols 2048+.
__global__ __launch_bounds__(256) void proj_kernel(
    const float* __restrict__ A, const float* __restrict__ Wk,
    const float* __restrict__ Wv, const float* __restrict__ g_ipk,
    unsigned short* __restrict__ Kb, unsigned short* __restrict__ Vt) {
  const float* W = blockIdx.z ? Wv : Wk;
  int h = blockIdx.x;
  int m0 = blockIdx.y * 32;
  __shared__ float As[16][36];
  __shared__ float Ws[16][132];
  int tid = threadIdx.x;
  int tx = tid & 31, ty = tid >> 5;   // cols tx*4..+3, rows ty*4..+3
  int am = tid >> 3, ak = (tid & 7) * 2;
  int wn = tid >> 1, wk = (tid & 1) * 8;
  const float* aptr = A + (long)(m0 + am) * DIP + ak;
  const float* wptr = W + (long)(h * Dh + wn) * DIP + wk;
  float acc[4][4] = {};
#pragma unroll 1
  for (int k0 = 0; k0 < DIP; k0 += 16) {
    float2 a2 = *(const float2*)(aptr + k0);
    float4 w4a = *(const float4*)(wptr + k0);
    float4 w4b = *(const float4*)(wptr + k0 + 4);
    __syncthreads();
    As[ak][am] = a2.x; As[ak + 1][am] = a2.y;
    Ws[wk + 0][wn] = w4a.x; Ws[wk + 1][wn] = w4a.y;
    Ws[wk + 2][wn] = w4a.z; Ws[wk + 3][wn] = w4a.w;
    Ws[wk + 4][wn] = w4b.x; Ws[wk + 5][wn] = w4b.y;
    Ws[wk + 6][wn] = w4b.z; Ws[wk + 7][wn] = w4b.w;
    __syncthreads();
#pragma unroll
    for (int kk = 0; kk < 16; kk++) {
      float4 av = *(const float4*)&As[kk][ty * 4];
      float4 wv = *(const float4*)&Ws[kk][tx * 4];
      float a_[4] = {av.x, av.y, av.z, av.w};
      float b_[4] = {wv.x, wv.y, wv.z, wv.w};
#pragma unroll
      for (int i = 0; i < 4; i++)
#pragma unroll
        for (int j = 0; j < 4; j++) acc[i][j] += a_[i] * b_[j];
    }
  }
  if (blockIdx.z == 0) {
    // RMS over the 128 cols (= head dim) per row, then bf16 -> Kb
#pragma unroll
    for (int i = 0; i < 4; i++) {
      float ssq = acc[i][0]*acc[i][0] + acc[i][1]*acc[i][1] +
                  acc[i][2]*acc[i][2] + acc[i][3]*acc[i][3];
      ssq += __shfl_xor(ssq, 1, 32);
      ssq += __shfl_xor(ssq, 2, 32);
      ssq += __shfl_xor(ssq, 4, 32);
      ssq += __shfl_xor(ssq, 8, 32);
      ssq += __shfl_xor(ssq, 16, 32);
      float rstd = rsqrtf(ssq * (1.f / Dh) + EPSF);
      ushort4 o;
      o.x = f2bf(acc[i][0] * rstd * g_ipk[tx * 4 + 0]);
      o.y = f2bf(acc[i][1] * rstd * g_ipk[tx * 4 + 1]);
      o.z = f2bf(acc[i][2] * rstd * g_ipk[tx * 4 + 2]);
      o.w = f2bf(acc[i][3] * rstd * g_ipk[tx * 4 + 3]);
      *(ushort4*)(Kb + ((long)h * LK + LIMG + m0 + ty * 4 + i) * Dh + tx * 4) = o;
    }
  } else {
#pragma unroll
    for (int j = 0; j < 4; j++) {
      ushort4 o;
      o.x = f2bf(acc[0][j]); o.y = f2bf(acc[1][j]);
      o.z = f2bf(acc[2][j]); o.w = f2bf(acc[3][j]);
      *(ushort4*)(Vt + ((long)h * Dh + tx * 4 + j) * LK + LIMG + m0 + ty * 4) = o;
    }
  }
}

// ---------------- Kernel 5: MFMA flash attention ----------------
// 4 waves; wave owns 16 q-rows (BQ=64). BK=32. Q fp32->RMS->bf16 in registers.
__global__ __launch_bounds__(256, 4) void flash_kernel(
    const float* __restrict__ q_in, const float* __restrict__ g_q,
    const unsigned short* __restrict__ Kb, const unsigned short* __restrict__ Vt,
    float* __restrict__ out) {
  __shared__ __align__(16) unsigned char lds[8192 + 8192 + 5120];
  unsigned short* Ks = (unsigned short*)lds;            // [32 rows][16 granules, XOR-swizzled]
  unsigned short* Vs = (unsigned short*)(lds + 8192);   // [128 d][4 granules]
  unsigned short* Ps = (unsigned short*)(lds + 16384);  // per wave: 16 rows x 40 ushorts
  int tid = threadIdx.x;
  int w = tid >> 6, lid = tid & 63;
  int m = lid & 15, quad = lid >> 4;
  int h = blockIdx.y;
  int q0 = blockIdx.x * 64;
  int qrow = q0 + w * 16 + m;

  // ---- Q: load fp32, RMS over 128 (quad lanes hold disjoint d), g_q, -> A-frags ----
  bf16x8 aq[4];
  {
    float qf[4][8];
    float ssq = 0.f;
    const float* qsrc = q_in + (long)qrow * DM + h * Dh + quad * 8;
#pragma unroll
    for (int ks = 0; ks < 4; ks++) {
      float4 a = *(const float4*)(qsrc + ks * 32);
      float4 b = *(const float4*)(qsrc + ks * 32 + 4);
      qf[ks][0]=a.x; qf[ks][1]=a.y; qf[ks][2]=a.z; qf[ks][3]=a.w;
      qf[ks][4]=b.x; qf[ks][5]=b.y; qf[ks][6]=b.z; qf[ks][7]=b.w;
      ssq += a.x*a.x + a.y*a.y + a.z*a.z + a.w*a.w;
      ssq += b.x*b.x + b.y*b.y + b.z*b.z + b.w*b.w;
    }
    ssq += __shfl_xor(ssq, 16, 64);
    ssq += __shfl_xor(ssq, 32, 64);
    float rstd = rsqrtf(ssq * (1.f / Dh) + EPSF);
    const float* gq = g_q + quad * 8;
#pragma unroll
    for (int ks = 0; ks < 4; ks++) {
      float4 ga = *(const float4*)(gq + ks * 32);
      float4 gb = *(const float4*)(gq + ks * 32 + 4);
      float gg[8] = {ga.x, ga.y, ga.z, ga.w, gb.x, gb.y, gb.z, gb.w};
#pragma unroll
      for (int j = 0; j < 8; j++)
        aq[ks][j] = (short)f2bf(qf[ks][j] * rstd * gg[j]);
    }
  }

  const unsigned short* KbH = Kb + (long)h * LK * Dh;
  const unsigned short* VtH = Vt + (long)h * Dh * LK;
  unsigned short* Pw = Ps + w * (16 * 40);

  f32x4 acc_o[8];
#pragma unroll
  for (int i = 0; i < 8; i++) acc_o[i] = (f32x4){0.f, 0.f, 0.f, 0.f};
  float mrun[4] = {-INFINITY, -INFINITY, -INFINITY, -INFINITY};
  float lrun[4] = {0.f, 0.f, 0.f, 0.f};

#pragma unroll 1
  for (int j0 = 0; j0 < LK; j0 += 32) {
    __syncthreads();   // all waves done reading previous tile
    {
      int sbase = w * 128;
#pragma unroll
      for (int is = 0; is < 2; is++) {   // K tile, swizzled via global address
        int s = sbase + is * 64 + lid;
        int r = s >> 4, cc = s & 15;
        int c = cc ^ (r & 15);
        const unsigned short* g = KbH + (long)(j0 + r) * Dh + c * 8;
        __builtin_amdgcn_global_load_lds((gu32*)g, (lu32*)(Ks + (sbase + is * 64) * 8),
                                         16, 0, 0);
      }
#pragma unroll
      for (int is = 0; is < 2; is++) {   // Vt tile (64B rows interleave banks naturally)
        int s = sbase + is * 64 + lid;
        int d = s >> 2, cc = s & 3;
        const unsigned short* g = VtH + (long)d * LK + j0 + cc * 8;
        __builtin_amdgcn_global_load_lds((gu32*)g, (lu32*)(Vs + (sbase + is * 64) * 8),
                                         16, 0, 0);
      }
    }
    __syncthreads();   // barrier drains vmcnt -> tiles ready

    // ---- S = Q K^T (two 16-wide n-tiles) ----
    f32x4 sc[2];
    sc[0] = (f32x4){0.f, 0.f, 0.f, 0.f};
    sc[1] = (f32x4){0.f, 0.f, 0.f, 0.f};
#pragma unroll
    for (int t = 0; t < 2; t++)
#pragma unroll
      for (int ks = 0; ks < 4; ks++) {
        int rr = t * 16 + m;
        int g = (ks * 4 + quad) ^ m;
        bf16x8 bk = *(const bf16x8*)(Ks + rr * 128 + g * 8);
        sc[t] = __builtin_amdgcn_mfma_f32_16x16x32_bf16(aq[ks], bk, sc[t], 0, 0, 0);
      }

    // ---- online softmax; lane holds rows quad*4+r, cols m and m+16 ----
    float mx[4], al[4], ps0[4], ps1[4];
#pragma unroll
    for (int r = 0; r < 4; r++) {
      float v0 = sc[0][r] * SM_SCALE, v1 = sc[1][r] * SM_SCALE;
      ps0[r] = v0; ps1[r] = v1;
      float mm = fmaxf(v0, v1);
      mm = fmaxf(mm, __shfl_xor(mm, 1, 16));
      mm = fmaxf(mm, __shfl_xor(mm, 2, 16));
      mm = fmaxf(mm, __shfl_xor(mm, 4, 16));
      mm = fmaxf(mm, __shfl_xor(mm, 8, 16));
      mx[r] = mm;
    }
#pragma unroll
    for (int r = 0; r < 4; r++) {
      float mn = fmaxf(mrun[r], mx[r]);
      al[r] = __expf(mrun[r] - mn);
      mrun[r] = mn;
      float p0 = __expf(ps0[r] - mn), p1 = __expf(ps1[r] - mn);
      ps0[r] = p0; ps1[r] = p1;
      float s2 = p0 + p1;
      s2 += __shfl_xor(s2, 1, 16);
      s2 += __shfl_xor(s2, 2, 16);
      s2 += __shfl_xor(s2, 4, 16);
      s2 += __shfl_xor(s2, 8, 16);
      lrun[r] = lrun[r] * al[r] + s2;
    }
    // ---- P: C-layout -> LDS -> A-layout (wave-private region, 80B stride) ----
#pragma unroll
    for (int r = 0; r < 4; r++) {
      Pw[(quad * 4 + r) * 40 + m] = f2bf(ps0[r]);
      Pw[(quad * 4 + r) * 40 + 16 + m] = f2bf(ps1[r]);
    }
    __threadfence_block();
    bf16x8 ap = *(const bf16x8*)(Pw + m * 40 + quad * 8);
#pragma unroll
    for (int dt = 0; dt < 8; dt++) {
      acc_o[dt][0] *= al[0]; acc_o[dt][1] *= al[1];
      acc_o[dt][2] *= al[2]; acc_o[dt][3] *= al[3];
    }
#pragma unroll
    for (int dt = 0; dt < 8; dt++) {
      bf16x8 bv = *(const bf16x8*)(Vs + (dt * 16 + m) * 32 + quad * 8);
      acc_o[dt] = __builtin_amdgcn_mfma_f32_16x16x32_bf16(ap, bv, acc_o[dt], 0, 0, 0);
    }
  }

  // ---- epilogue ----
  float il[4] = {1.f / lrun[0], 1.f / lrun[1], 1.f / lrun[2], 1.f / lrun[3]};
#pragma unroll
  for (int dt = 0; dt < 8; dt++)
#pragma unroll
    for (int r = 0; r < 4; r++)
      out[(long)(q0 + w * 16 + quad * 4 + r) * DM + h * Dh + dt * 16 + m] =
          acc_o[dt][r] * il[r];
}

// ---------------- launch ----------------
extern "C" void kernel_launch(void* const* d_in, const int* in_sizes, int n_in,
                              void* d_out, int out_size, void* d_ws, size_t ws_size,
                              hipStream_t stream) {
  const float* ip_hidden = (const float*)d_in[0];
  const float* img_q     = (const float*)d_in[1];
  const float* img_k     = (const float*)d_in[2];
  const float* img_v     = (const float*)d_in[3];
  const float* t_emb     = (const float*)d_in[4];
  const float* w_ada     = (const float*)d_in[5];
  const float* b_ada     = (const float*)d_in[6];
  const float* w_k_ip    = (const float*)d_in[7];
  const float* w_v_ip    = (const float*)d_in[8];
  const float* g_q       = (const float*)d_in[9];
  const float* g_k       = (const float*)d_in[10];
  const float* g_ipk     = (const float*)d_in[11];

  float* ws  = (float*)d_ws;
  float* e   = ws;                          // 2560 used (4096 reserved)
  float* ipn = ws + 4096;                   // 512*1280 fp32
  unsigned char* bbase = (unsigned char*)d_ws + (size_t)(4096 + LIP * DIP) * 4;
  unsigned short* Kb = (unsigned short*)bbase;                       // 24*2560*128 bf16
  unsigned short* Vt = Kb + (size_t)H * LK * Dh;                     // 24*128*2560 bf16
  float* out = (float*)d_out;

  ada_kernel<<<2 * DIP, 256, 0, stream>>>(t_emb, w_ada, b_ada, e);
  adaln_kernel<<<LIP, 256, 0, stream>>>(ip_hidden, e, ipn);
  prep_kernel<<<dim3(LIMG / 32, H), 256, 0, stream>>>(img_k, img_v, g_k, Kb, Vt);
  proj_kernel<<<dim3(H, LIP / 32, 2), 256, 0, stream>>>(ipn, w_k_ip, w_v_ip, g_ipk, Kb, Vt);
  flash_kernel<<<dim3(LIMG / 64, H), 256, 0, stream>>>(img_q, g_q, Kb, Vt, out);
}